// Round 4
// baseline (149.544 us; speedup 1.0000x reference)
//
#include <hip/hip_runtime.h>
#include <hip/hip_bf16.h>

// GConv: out = relu( Agg(support) + x@loop_W + bias )
// R3: single fused MFMA dispatch computes BOTH products (support bf16, out f32),
//     staging A directly from f32 X (cvt fused). 1024-thread scan. Fewer launches.

#define NN 10000
#define DK 256
#define DO 256
#define MT 20000      // B*N rows
#define SCAN_T 1024
#define SCAN_C 10     // 10240 >= NN

typedef short short8 __attribute__((ext_vector_type(8)));
typedef float f32x4 __attribute__((ext_vector_type(4)));

__device__ inline unsigned short f2bf(float f) {
    unsigned int u = __float_as_uint(f);
    u = (u + 0x7FFFu + ((u >> 16) & 1u)) >> 16;   // round-nearest-even
    return (unsigned short)u;
}
__device__ inline float bf2f(unsigned short s) {
    return __uint_as_float(((unsigned int)s) << 16);
}

// ---------------- transpose+convert W,LW -> Wt,LWt (bf16 [col][k]); z=0 also zeros counts ----------------
__global__ __launch_bounds__(256) void transpose_w(
    const float* __restrict__ W, const float* __restrict__ LW,
    unsigned short* __restrict__ Wt, unsigned short* __restrict__ LWt,
    int* __restrict__ counts)
{
    __shared__ float tile[64][65];
    const float* src = blockIdx.z ? LW : W;
    unsigned short* dst = blockIdx.z ? LWt : Wt;
    const int k0 = blockIdx.x * 64, c0 = blockIdx.y * 64;

    if (blockIdx.z == 0) {   // 16 blocks x 256 threads zero 10000 counters
        const int bid = blockIdx.x * 4 + blockIdx.y;
        const int i = bid * 256 * 3 + threadIdx.x;   // stride-3 coverage: 16*768=12288>=NN
        #pragma unroll
        for (int q = 0; q < 3; ++q) {
            const int idx = i + q * 256;
            if (idx < NN) counts[idx] = 0;
        }
    }

    #pragma unroll
    for (int it = 0; it < 16; ++it) {
        const int u = it * 256 + threadIdx.x;
        const int i = u >> 6, j = u & 63;
        tile[i][j] = src[(size_t)(k0 + i) * DO + c0 + j];
    }
    __syncthreads();
    #pragma unroll
    for (int it = 0; it < 16; ++it) {
        const int u = it * 256 + threadIdx.x;
        const int j = u >> 6, i = u & 63;
        dst[(size_t)(c0 + j) * DK + k0 + i] = f2bf(tile[i][j]);
    }
}

// ---------------- fused dual MFMA GEMM ----------------
// One dispatch: sup = bf16(X@W), outv = X@LW + bias (f32).
// block 256 = 4 waves (2x2), block tile 128x128, wave tile 64x64 per product, BK=64.
__global__ __launch_bounds__(256) void gemm_fused(
    const float* __restrict__ X, const unsigned short* __restrict__ Wt,
    const unsigned short* __restrict__ LWt, const float* __restrict__ bias,
    unsigned short* __restrict__ sup, float* __restrict__ outv)
{
    __shared__ unsigned short As[8][128][8];
    __shared__ unsigned short BsW[8][128][8];
    __shared__ unsigned short BsL[8][128][8];
    const int t = threadIdx.x;
    const int wid = t >> 6, lane = t & 63;
    const int wm = wid >> 1, wn = wid & 1;
    const int m0 = blockIdx.x * 128;
    const int n0 = blockIdx.y * 128;

    f32x4 accW[4][4], accL[4][4];
    #pragma unroll
    for (int i = 0; i < 4; ++i)
        #pragma unroll
        for (int j = 0; j < 4; ++j) {
            accW[i][j] = (f32x4){0.f, 0.f, 0.f, 0.f};
            accL[i][j] = (f32x4){0.f, 0.f, 0.f, 0.f};
        }

    for (int k0 = 0; k0 < DK; k0 += 64) {
        // stage A from f32 X, convert to bf16
        #pragma unroll
        for (int it = 0; it < 4; ++it) {
            const int u = it * 256 + t;
            const int row = u >> 3, kg = u & 7;
            const int grow = m0 + row;
            short8 v = (short8){0,0,0,0,0,0,0,0};
            if (grow < MT) {
                const float4 a = *(const float4*)&X[(size_t)grow * DK + k0 + kg * 8];
                const float4 b = *(const float4*)&X[(size_t)grow * DK + k0 + kg * 8 + 4];
                v[0] = (short)f2bf(a.x); v[1] = (short)f2bf(a.y);
                v[2] = (short)f2bf(a.z); v[3] = (short)f2bf(a.w);
                v[4] = (short)f2bf(b.x); v[5] = (short)f2bf(b.y);
                v[6] = (short)f2bf(b.z); v[7] = (short)f2bf(b.w);
            }
            *(short8*)&As[kg][row ^ kg][0] = v;
        }
        // stage B tiles (bf16 [col][k] layout, contiguous short8)
        #pragma unroll
        for (int it = 0; it < 4; ++it) {
            const int u = it * 256 + t;
            const int col = u >> 3, kg = u & 7;
            const size_t off = (size_t)(n0 + col) * DK + k0 + kg * 8;
            *(short8*)&BsW[kg][col ^ kg][0] = *(const short8*)&Wt[off];
            *(short8*)&BsL[kg][col ^ kg][0] = *(const short8*)&LWt[off];
        }
        __syncthreads();
        #pragma unroll
        for (int s = 0; s < 2; ++s) {             // two k=32 substeps
            const int kg = s * 4 + (lane >> 4);
            short8 af[4], bW[4], bL[4];
            #pragma unroll
            for (int i = 0; i < 4; ++i) {
                const int row = wm * 64 + i * 16 + (lane & 15);
                af[i] = *(const short8*)&As[kg][row ^ kg][0];
            }
            #pragma unroll
            for (int j = 0; j < 4; ++j) {
                const int col = wn * 64 + j * 16 + (lane & 15);
                bW[j] = *(const short8*)&BsW[kg][col ^ kg][0];
                bL[j] = *(const short8*)&BsL[kg][col ^ kg][0];
            }
            #pragma unroll
            for (int i = 0; i < 4; ++i)
                #pragma unroll
                for (int j = 0; j < 4; ++j) {
                    accW[i][j] = __builtin_amdgcn_mfma_f32_16x16x32_bf16(
                        af[i], bW[j], accW[i][j], 0, 0, 0);
                    accL[i][j] = __builtin_amdgcn_mfma_f32_16x16x32_bf16(
                        af[i], bL[j], accL[i][j], 0, 0, 0);
                }
        }
        __syncthreads();
    }

    const int rbase = m0 + wm * 64;
    const int cbase = n0 + wn * 64;
    #pragma unroll
    for (int i = 0; i < 4; ++i)
        #pragma unroll
        for (int q = 0; q < 4; ++q) {
            const int row = rbase + i * 16 + (lane >> 4) * 4 + q;
            if (row < MT) {
                #pragma unroll
                for (int j = 0; j < 4; ++j) {
                    const int col = cbase + j * 16 + (lane & 15);
                    sup[(size_t)row * DO + col] = f2bf(accW[i][j][q]);
                    outv[(size_t)row * DO + col] = accL[i][j][q] + bias[col];
                }
            }
        }
}

// ---------------- CSR build ----------------
__global__ __launch_bounds__(256) void hist_rows(
    const int* __restrict__ rows, int* __restrict__ counts, int E)
{
    const int e = blockIdx.x * 256 + threadIdx.x;
    if (e < E) atomicAdd(&counts[rows[e]], 1);
}

__global__ __launch_bounds__(SCAN_T) void scan_rows(
    const int* __restrict__ counts, int* __restrict__ offsets,
    int* __restrict__ cursor)
{
    __shared__ int sums[SCAN_T];
    const int t = threadIdx.x;
    int local[SCAN_C];
    int s = 0;
    const int base = t * SCAN_C;
    #pragma unroll
    for (int i = 0; i < SCAN_C; ++i) {
        const int idx = base + i;
        const int c = (idx < NN) ? counts[idx] : 0;
        local[i] = s;
        s += c;
    }
    sums[t] = s;
    __syncthreads();
    for (int off = 1; off < SCAN_T; off <<= 1) {
        int u = (t >= off) ? sums[t - off] : 0;
        __syncthreads();
        sums[t] += u;
        __syncthreads();
    }
    const int excl = (t == 0) ? 0 : sums[t - 1];
    #pragma unroll
    for (int i = 0; i < SCAN_C; ++i) {
        const int idx = base + i;
        if (idx < NN) {
            const int o = excl + local[i];
            offsets[idx] = o;
            cursor[idx]  = o;
        }
    }
}

__global__ __launch_bounds__(256) void scatter_edges(
    const int* __restrict__ rows, const int* __restrict__ cols,
    const float* __restrict__ vals, int* __restrict__ cursor,
    float2* __restrict__ epack, int E)
{
    const int e = blockIdx.x * 256 + threadIdx.x;
    if (e >= E) return;
    const int p = atomicAdd(&cursor[rows[e]], 1);
    epack[p] = make_float2(__int_as_float(cols[e]), vals[e]);
}

// ---------------- aggregate + ReLU: one wave per (row, batch) ----------------
__global__ __launch_bounds__(256) void agg_relu(
    const unsigned short* __restrict__ sup, const float2* __restrict__ epack,
    const int* __restrict__ offsets, const int* __restrict__ counts,
    float* __restrict__ outv)
{
    const int widx = (blockIdx.x * 256 + threadIdx.x) >> 6;
    if (widx >= 2 * NN) return;
    const int lane = threadIdx.x & 63;
    const int b = widx & 1, r = widx >> 1;
    const int d = lane * 4;
    const size_t supb = (size_t)b * NN * DO + d;
    const int start = offsets[r];
    const int deg   = counts[r];

    float a0 = 0.f, a1 = 0.f, a2 = 0.f, a3 = 0.f;
    #pragma unroll 8
    for (int i = 0; i < deg; ++i) {
        const float2 ep = epack[start + i];
        const int col = __float_as_int(ep.x);
        const float v = ep.y;
        const ushort4 s = *(const ushort4*)&sup[supb + (size_t)col * DO];
        a0 += v * bf2f(s.x); a1 += v * bf2f(s.y);
        a2 += v * bf2f(s.z); a3 += v * bf2f(s.w);
    }

    float* o = &outv[((size_t)b * NN + r) * DO + d];
    float4 t4 = *(const float4*)o;
    t4.x = fmaxf(t4.x + a0, 0.f); t4.y = fmaxf(t4.y + a1, 0.f);
    t4.z = fmaxf(t4.z + a2, 0.f); t4.w = fmaxf(t4.w + a3, 0.f);
    *(float4*)o = t4;
}

extern "C" void kernel_launch(void* const* d_in, const int* in_sizes, int n_in,
                              void* d_out, int out_size, void* d_ws, size_t ws_size,
                              hipStream_t stream)
{
    const float* x    = (const float*)d_in[0];
    const float* W    = (const float*)d_in[1];
    const float* LW   = (const float*)d_in[2];
    const float* bias = (const float*)d_in[3];
    const float* ev   = (const float*)d_in[4];
    const int*   rows = (const int*)d_in[5];
    const int*   cols = (const int*)d_in[6];
    float* out = (float*)d_out;

    const int E = in_sizes[4];

    // workspace layout
    char* wsb = (char*)d_ws;
    unsigned short* Wt    = (unsigned short*)wsb;              // 131,072 B
    unsigned short* LWt   = (unsigned short*)(wsb + 131072);   // 131,072 B
    unsigned short* supb  = (unsigned short*)(wsb + 262144);   // 10,240,000 B
    int* counts  = (int*)(wsb + 10502144);                     // 40,000 B
    int* offsets = (int*)(wsb + 10542144);                     // 40,000 B
    int* cursor  = (int*)(wsb + 10582144);                     // 40,000 B
    float2* epack = (float2*)(wsb + 10622144);                 // 8*E B

    transpose_w<<<dim3(4, 4, 2), 256, 0, stream>>>(W, LW, Wt, LWt, counts);
    hist_rows<<<(E + 255) / 256, 256, 0, stream>>>(rows, counts, E);
    scan_rows<<<1, SCAN_T, 0, stream>>>(counts, offsets, cursor);

    gemm_fused<<<dim3((MT + 127) / 128, DO / 128), 256, 0, stream>>>(
        x, Wt, LWt, bias, supb, out);

    scatter_edges<<<(E + 255) / 256, 256, 0, stream>>>(rows, cols, ev, cursor, epack, E);

    const int aggBlocks = (2 * NN * 64 + 255) / 256;
    agg_relu<<<aggBlocks, 256, 0, stream>>>(supb, epack, offsets, counts, out);
}

// Round 5
// 128.068 us; speedup vs baseline: 1.1677x; 1.1677x over previous
//
#include <hip/hip_runtime.h>
#include <hip/hip_bf16.h>

// GConv: out = relu( Agg(support) + x@loop_W + bias )
// R4: fused dual GEMM with 64x64 tiles (grid 1252 blocks) to fix the
//     occupancy collapse of R3's 128x128 fused tile. Rest unchanged.

#define NN 10000
#define DK 256
#define DO 256
#define MT 20000      // B*N rows
#define SCAN_T 1024
#define SCAN_C 10     // 10240 >= NN

typedef short short8 __attribute__((ext_vector_type(8)));
typedef float f32x4 __attribute__((ext_vector_type(4)));

__device__ inline unsigned short f2bf(float f) {
    unsigned int u = __float_as_uint(f);
    u = (u + 0x7FFFu + ((u >> 16) & 1u)) >> 16;   // round-nearest-even
    return (unsigned short)u;
}
__device__ inline float bf2f(unsigned short s) {
    return __uint_as_float(((unsigned int)s) << 16);
}

// ---------------- transpose+convert W,LW -> Wt,LWt (bf16 [col][k]); z=0 also zeros counts ----------------
__global__ __launch_bounds__(256) void transpose_w(
    const float* __restrict__ W, const float* __restrict__ LW,
    unsigned short* __restrict__ Wt, unsigned short* __restrict__ LWt,
    int* __restrict__ counts)
{
    __shared__ float tile[64][65];
    const float* src = blockIdx.z ? LW : W;
    unsigned short* dst = blockIdx.z ? LWt : Wt;
    const int k0 = blockIdx.x * 64, c0 = blockIdx.y * 64;

    if (blockIdx.z == 0) {   // 16 blocks x 256 threads x 3 zero 10000 counters
        const int bid = blockIdx.x * 4 + blockIdx.y;
        const int i = bid * 256 * 3 + threadIdx.x;
        #pragma unroll
        for (int q = 0; q < 3; ++q) {
            const int idx = i + q * 256;
            if (idx < NN) counts[idx] = 0;
        }
    }

    #pragma unroll
    for (int it = 0; it < 16; ++it) {
        const int u = it * 256 + threadIdx.x;
        const int i = u >> 6, j = u & 63;
        tile[i][j] = src[(size_t)(k0 + i) * DO + c0 + j];
    }
    __syncthreads();
    #pragma unroll
    for (int it = 0; it < 16; ++it) {
        const int u = it * 256 + threadIdx.x;
        const int j = u >> 6, i = u & 63;
        dst[(size_t)(c0 + j) * DK + k0 + i] = f2bf(tile[i][j]);
    }
}

// ---------------- fused dual MFMA GEMM, 64x64 tile ----------------
// sup = bf16(X@W), outv = X@LW + bias (f32). 4 waves (2x2), wave tile 32x32/product.
__global__ __launch_bounds__(256) void gemm_fused(
    const float* __restrict__ X, const unsigned short* __restrict__ Wt,
    const unsigned short* __restrict__ LWt, const float* __restrict__ bias,
    unsigned short* __restrict__ sup, float* __restrict__ outv)
{
    __shared__ unsigned short As[8][64][8];
    __shared__ unsigned short BsW[8][64][8];
    __shared__ unsigned short BsL[8][64][8];
    const int t = threadIdx.x;
    const int wid = t >> 6, lane = t & 63;
    const int wm = wid >> 1, wn = wid & 1;
    const int m0 = blockIdx.x * 64;
    const int n0 = blockIdx.y * 64;

    f32x4 accW[2][2], accL[2][2];
    #pragma unroll
    for (int i = 0; i < 2; ++i)
        #pragma unroll
        for (int j = 0; j < 2; ++j) {
            accW[i][j] = (f32x4){0.f, 0.f, 0.f, 0.f};
            accL[i][j] = (f32x4){0.f, 0.f, 0.f, 0.f};
        }

    for (int k0 = 0; k0 < DK; k0 += 64) {
        // stage A from f32 X (convert to bf16): 64 rows x 8 kgroups, 2 per thread
        #pragma unroll
        for (int it = 0; it < 2; ++it) {
            const int u = it * 256 + t;
            const int row = u >> 3, kg = u & 7;
            const int grow = m0 + row;
            short8 v = (short8){0,0,0,0,0,0,0,0};
            if (grow < MT) {
                const float4 a = *(const float4*)&X[(size_t)grow * DK + k0 + kg * 8];
                const float4 b = *(const float4*)&X[(size_t)grow * DK + k0 + kg * 8 + 4];
                v[0] = (short)f2bf(a.x); v[1] = (short)f2bf(a.y);
                v[2] = (short)f2bf(a.z); v[3] = (short)f2bf(a.w);
                v[4] = (short)f2bf(b.x); v[5] = (short)f2bf(b.y);
                v[6] = (short)f2bf(b.z); v[7] = (short)f2bf(b.w);
            }
            *(short8*)&As[kg][row ^ kg][0] = v;
        }
        // stage B tiles (bf16 [col][k], contiguous short8)
        #pragma unroll
        for (int it = 0; it < 2; ++it) {
            const int u = it * 256 + t;
            const int col = u >> 3, kg = u & 7;
            const size_t off = (size_t)(n0 + col) * DK + k0 + kg * 8;
            *(short8*)&BsW[kg][col ^ kg][0] = *(const short8*)&Wt[off];
            *(short8*)&BsL[kg][col ^ kg][0] = *(const short8*)&LWt[off];
        }
        __syncthreads();
        #pragma unroll
        for (int s = 0; s < 2; ++s) {             // two k=32 substeps
            const int kg = s * 4 + (lane >> 4);
            short8 af[2], bW[2], bL[2];
            #pragma unroll
            for (int i = 0; i < 2; ++i) {
                const int row = wm * 32 + i * 16 + (lane & 15);
                af[i] = *(const short8*)&As[kg][row ^ kg][0];
            }
            #pragma unroll
            for (int j = 0; j < 2; ++j) {
                const int col = wn * 32 + j * 16 + (lane & 15);
                bW[j] = *(const short8*)&BsW[kg][col ^ kg][0];
                bL[j] = *(const short8*)&BsL[kg][col ^ kg][0];
            }
            #pragma unroll
            for (int i = 0; i < 2; ++i)
                #pragma unroll
                for (int j = 0; j < 2; ++j) {
                    accW[i][j] = __builtin_amdgcn_mfma_f32_16x16x32_bf16(
                        af[i], bW[j], accW[i][j], 0, 0, 0);
                    accL[i][j] = __builtin_amdgcn_mfma_f32_16x16x32_bf16(
                        af[i], bL[j], accL[i][j], 0, 0, 0);
                }
        }
        __syncthreads();
    }

    const int rbase = m0 + wm * 32;
    const int cbase = n0 + wn * 32;
    #pragma unroll
    for (int i = 0; i < 2; ++i)
        #pragma unroll
        for (int q = 0; q < 4; ++q) {
            const int row = rbase + i * 16 + (lane >> 4) * 4 + q;
            if (row < MT) {
                #pragma unroll
                for (int j = 0; j < 2; ++j) {
                    const int col = cbase + j * 16 + (lane & 15);
                    sup[(size_t)row * DO + col] = f2bf(accW[i][j][q]);
                    outv[(size_t)row * DO + col] = accL[i][j][q] + bias[col];
                }
            }
        }
}

// ---------------- CSR build ----------------
__global__ __launch_bounds__(256) void hist_rows(
    const int* __restrict__ rows, int* __restrict__ counts, int E)
{
    const int e = blockIdx.x * 256 + threadIdx.x;
    if (e < E) atomicAdd(&counts[rows[e]], 1);
}

__global__ __launch_bounds__(SCAN_T) void scan_rows(
    const int* __restrict__ counts, int* __restrict__ offsets,
    int* __restrict__ cursor)
{
    __shared__ int sums[SCAN_T];
    const int t = threadIdx.x;
    int local[SCAN_C];
    int s = 0;
    const int base = t * SCAN_C;
    #pragma unroll
    for (int i = 0; i < SCAN_C; ++i) {
        const int idx = base + i;
        const int c = (idx < NN) ? counts[idx] : 0;
        local[i] = s;
        s += c;
    }
    sums[t] = s;
    __syncthreads();
    for (int off = 1; off < SCAN_T; off <<= 1) {
        int u = (t >= off) ? sums[t - off] : 0;
        __syncthreads();
        sums[t] += u;
        __syncthreads();
    }
    const int excl = (t == 0) ? 0 : sums[t - 1];
    #pragma unroll
    for (int i = 0; i < SCAN_C; ++i) {
        const int idx = base + i;
        if (idx < NN) {
            const int o = excl + local[i];
            offsets[idx] = o;
            cursor[idx]  = o;
        }
    }
}

__global__ __launch_bounds__(256) void scatter_edges(
    const int* __restrict__ rows, const int* __restrict__ cols,
    const float* __restrict__ vals, int* __restrict__ cursor,
    float2* __restrict__ epack, int E)
{
    const int e = blockIdx.x * 256 + threadIdx.x;
    if (e >= E) return;
    const int p = atomicAdd(&cursor[rows[e]], 1);
    epack[p] = make_float2(__int_as_float(cols[e]), vals[e]);
}

// ---------------- aggregate + ReLU: one wave per (row, batch) ----------------
__global__ __launch_bounds__(256) void agg_relu(
    const unsigned short* __restrict__ sup, const float2* __restrict__ epack,
    const int* __restrict__ offsets, const int* __restrict__ counts,
    float* __restrict__ outv)
{
    const int widx = (blockIdx.x * 256 + threadIdx.x) >> 6;
    if (widx >= 2 * NN) return;
    const int lane = threadIdx.x & 63;
    const int b = widx & 1, r = widx >> 1;
    const int d = lane * 4;
    const size_t supb = (size_t)b * NN * DO + d;
    const int start = offsets[r];
    const int deg   = counts[r];

    float a0 = 0.f, a1 = 0.f, a2 = 0.f, a3 = 0.f;
    #pragma unroll 8
    for (int i = 0; i < deg; ++i) {
        const float2 ep = epack[start + i];
        const int col = __float_as_int(ep.x);
        const float v = ep.y;
        const ushort4 s = *(const ushort4*)&sup[supb + (size_t)col * DO];
        a0 += v * bf2f(s.x); a1 += v * bf2f(s.y);
        a2 += v * bf2f(s.z); a3 += v * bf2f(s.w);
    }

    float* o = &outv[((size_t)b * NN + r) * DO + d];
    float4 t4 = *(const float4*)o;
    t4.x = fmaxf(t4.x + a0, 0.f); t4.y = fmaxf(t4.y + a1, 0.f);
    t4.z = fmaxf(t4.z + a2, 0.f); t4.w = fmaxf(t4.w + a3, 0.f);
    *(float4*)o = t4;
}

extern "C" void kernel_launch(void* const* d_in, const int* in_sizes, int n_in,
                              void* d_out, int out_size, void* d_ws, size_t ws_size,
                              hipStream_t stream)
{
    const float* x    = (const float*)d_in[0];
    const float* W    = (const float*)d_in[1];
    const float* LW   = (const float*)d_in[2];
    const float* bias = (const float*)d_in[3];
    const float* ev   = (const float*)d_in[4];
    const int*   rows = (const int*)d_in[5];
    const int*   cols = (const int*)d_in[6];
    float* out = (float*)d_out;

    const int E = in_sizes[4];

    // workspace layout
    char* wsb = (char*)d_ws;
    unsigned short* Wt    = (unsigned short*)wsb;              // 131,072 B
    unsigned short* LWt   = (unsigned short*)(wsb + 131072);   // 131,072 B
    unsigned short* supb  = (unsigned short*)(wsb + 262144);   // 10,240,000 B
    int* counts  = (int*)(wsb + 10502144);                     // 40,000 B
    int* offsets = (int*)(wsb + 10542144);                     // 40,000 B
    int* cursor  = (int*)(wsb + 10582144);                     // 40,000 B
    float2* epack = (float2*)(wsb + 10622144);                 // 8*E B

    transpose_w<<<dim3(4, 4, 2), 256, 0, stream>>>(W, LW, Wt, LWt, counts);
    hist_rows<<<(E + 255) / 256, 256, 0, stream>>>(rows, counts, E);
    scan_rows<<<1, SCAN_T, 0, stream>>>(counts, offsets, cursor);

    gemm_fused<<<dim3((MT + 63) / 64, DO / 64), 256, 0, stream>>>(
        x, Wt, LWt, bias, supb, out);

    scatter_edges<<<(E + 255) / 256, 256, 0, stream>>>(rows, cols, ev, cursor, epack, E);

    const int aggBlocks = (2 * NN * 64 + 255) / 256;
    agg_relu<<<aggBlocks, 256, 0, stream>>>(supb, epack, offsets, counts, out);
}

// Round 6
// 121.114 us; speedup vs baseline: 1.2347x; 1.0574x over previous
//
#include <hip/hip_runtime.h>
#include <hip/hip_bf16.h>

// GConv: out = relu( Agg(support) + x@loop_W + bias )
// R5: fuse independent stages into shared dispatches:
//     memset(counts) -> prep{transpose_w | hist} -> scan -> main{gemm | scatter} -> agg.
//     Scatter and hist run concurrently with (and hidden under) transpose/gemm.

#define NN 10000
#define DK 256
#define DO 256
#define MT 20000      // B*N rows
#define SCAN_T 1024
#define SCAN_C 10     // 10240 >= NN

typedef short short8 __attribute__((ext_vector_type(8)));
typedef float f32x4 __attribute__((ext_vector_type(4)));

__device__ inline unsigned short f2bf(float f) {
    unsigned int u = __float_as_uint(f);
    u = (u + 0x7FFFu + ((u >> 16) & 1u)) >> 16;   // round-nearest-even
    return (unsigned short)u;
}
__device__ inline float bf2f(unsigned short s) {
    return __uint_as_float(((unsigned int)s) << 16);
}

// ---------------- prep: blocks [0,32) transpose W/LW -> bf16 [col][k]; rest: row histogram ----------------
__global__ __launch_bounds__(256) void prep_kernel(
    const float* __restrict__ W, const float* __restrict__ LW,
    unsigned short* __restrict__ Wt, unsigned short* __restrict__ LWt,
    const int* __restrict__ rows, int* __restrict__ counts, int E)
{
    __shared__ float tile[64][65];
    const int bid = blockIdx.x;
    if (bid < 32) {
        const int z = bid >> 4, rem = bid & 15;
        const int k0 = (rem >> 2) * 64, c0 = (rem & 3) * 64;
        const float* src = z ? LW : W;
        unsigned short* dst = z ? LWt : Wt;
        #pragma unroll
        for (int it = 0; it < 16; ++it) {
            const int u = it * 256 + threadIdx.x;
            const int i = u >> 6, j = u & 63;
            tile[i][j] = src[(size_t)(k0 + i) * DO + c0 + j];
        }
        __syncthreads();
        #pragma unroll
        for (int it = 0; it < 16; ++it) {
            const int u = it * 256 + threadIdx.x;
            const int j = u >> 6, i = u & 63;
            dst[(size_t)(c0 + j) * DK + k0 + i] = f2bf(tile[i][j]);
        }
    } else {
        const int e = (bid - 32) * 256 + threadIdx.x;
        if (e < E) atomicAdd(&counts[rows[e]], 1);
    }
}

// ---------------- scan: exclusive prefix over counts -> offsets, cursor ----------------
__global__ __launch_bounds__(SCAN_T) void scan_rows(
    const int* __restrict__ counts, int* __restrict__ offsets,
    int* __restrict__ cursor)
{
    __shared__ int sums[SCAN_T];
    const int t = threadIdx.x;
    int local[SCAN_C];
    int s = 0;
    const int base = t * SCAN_C;
    #pragma unroll
    for (int i = 0; i < SCAN_C; ++i) {
        const int idx = base + i;
        const int c = (idx < NN) ? counts[idx] : 0;
        local[i] = s;
        s += c;
    }
    sums[t] = s;
    __syncthreads();
    for (int off = 1; off < SCAN_T; off <<= 1) {
        int u = (t >= off) ? sums[t - off] : 0;
        __syncthreads();
        sums[t] += u;
        __syncthreads();
    }
    const int excl = (t == 0) ? 0 : sums[t - 1];
    #pragma unroll
    for (int i = 0; i < SCAN_C; ++i) {
        const int idx = base + i;
        if (idx < NN) {
            const int o = excl + local[i];
            offsets[idx] = o;
            cursor[idx]  = o;
        }
    }
}

// ---------------- main: blocks [0,gemmBlocks) fused dual GEMM; rest: edge scatter ----------------
// GEMM: 64x64 block tile, 4 waves (2x2), wave tile 32x32 per product, BK=64.
// sup = bf16(X@W), outv = X@LW + bias (f32).
__global__ __launch_bounds__(256) void main_kernel(
    const float* __restrict__ X, const unsigned short* __restrict__ Wt,
    const unsigned short* __restrict__ LWt, const float* __restrict__ bias,
    unsigned short* __restrict__ sup, float* __restrict__ outv,
    const int* __restrict__ rows, const int* __restrict__ cols,
    const float* __restrict__ vals, int* __restrict__ cursor,
    float2* __restrict__ epack, int E, int gemmBlocks)
{
    __shared__ unsigned short As[8][64][8];
    __shared__ unsigned short BsW[8][64][8];
    __shared__ unsigned short BsL[8][64][8];

    if (blockIdx.x >= gemmBlocks) {
        const int e = (blockIdx.x - gemmBlocks) * 256 + threadIdx.x;
        if (e < E) {
            const int p = atomicAdd(&cursor[rows[e]], 1);
            epack[p] = make_float2(__int_as_float(cols[e]), vals[e]);
        }
        return;
    }

    const int t = threadIdx.x;
    const int wid = t >> 6, lane = t & 63;
    const int wm = wid >> 1, wn = wid & 1;
    const int m0 = (blockIdx.x >> 2) * 64;
    const int n0 = (blockIdx.x & 3) * 64;

    f32x4 accW[2][2], accL[2][2];
    #pragma unroll
    for (int i = 0; i < 2; ++i)
        #pragma unroll
        for (int j = 0; j < 2; ++j) {
            accW[i][j] = (f32x4){0.f, 0.f, 0.f, 0.f};
            accL[i][j] = (f32x4){0.f, 0.f, 0.f, 0.f};
        }

    for (int k0 = 0; k0 < DK; k0 += 64) {
        #pragma unroll
        for (int it = 0; it < 2; ++it) {          // stage A (f32 -> bf16)
            const int u = it * 256 + t;
            const int row = u >> 3, kg = u & 7;
            const int grow = m0 + row;
            short8 v = (short8){0,0,0,0,0,0,0,0};
            if (grow < MT) {
                const float4 a = *(const float4*)&X[(size_t)grow * DK + k0 + kg * 8];
                const float4 b = *(const float4*)&X[(size_t)grow * DK + k0 + kg * 8 + 4];
                v[0] = (short)f2bf(a.x); v[1] = (short)f2bf(a.y);
                v[2] = (short)f2bf(a.z); v[3] = (short)f2bf(a.w);
                v[4] = (short)f2bf(b.x); v[5] = (short)f2bf(b.y);
                v[6] = (short)f2bf(b.z); v[7] = (short)f2bf(b.w);
            }
            *(short8*)&As[kg][row ^ kg][0] = v;
        }
        #pragma unroll
        for (int it = 0; it < 2; ++it) {          // stage B tiles
            const int u = it * 256 + t;
            const int col = u >> 3, kg = u & 7;
            const size_t off = (size_t)(n0 + col) * DK + k0 + kg * 8;
            *(short8*)&BsW[kg][col ^ kg][0] = *(const short8*)&Wt[off];
            *(short8*)&BsL[kg][col ^ kg][0] = *(const short8*)&LWt[off];
        }
        __syncthreads();
        #pragma unroll
        for (int s = 0; s < 2; ++s) {             // two k=32 substeps
            const int kg = s * 4 + (lane >> 4);
            short8 af[2], bW[2], bL[2];
            #pragma unroll
            for (int i = 0; i < 2; ++i) {
                const int row = wm * 32 + i * 16 + (lane & 15);
                af[i] = *(const short8*)&As[kg][row ^ kg][0];
            }
            #pragma unroll
            for (int j = 0; j < 2; ++j) {
                const int col = wn * 32 + j * 16 + (lane & 15);
                bW[j] = *(const short8*)&BsW[kg][col ^ kg][0];
                bL[j] = *(const short8*)&BsL[kg][col ^ kg][0];
            }
            #pragma unroll
            for (int i = 0; i < 2; ++i)
                #pragma unroll
                for (int j = 0; j < 2; ++j) {
                    accW[i][j] = __builtin_amdgcn_mfma_f32_16x16x32_bf16(
                        af[i], bW[j], accW[i][j], 0, 0, 0);
                    accL[i][j] = __builtin_amdgcn_mfma_f32_16x16x32_bf16(
                        af[i], bL[j], accL[i][j], 0, 0, 0);
                }
        }
        __syncthreads();
    }

    const int rbase = m0 + wm * 32;
    const int cbase = n0 + wn * 32;
    #pragma unroll
    for (int i = 0; i < 2; ++i)
        #pragma unroll
        for (int q = 0; q < 4; ++q) {
            const int row = rbase + i * 16 + (lane >> 4) * 4 + q;
            if (row < MT) {
                #pragma unroll
                for (int j = 0; j < 2; ++j) {
                    const int col = cbase + j * 16 + (lane & 15);
                    sup[(size_t)row * DO + col] = f2bf(accW[i][j][q]);
                    outv[(size_t)row * DO + col] = accL[i][j][q] + bias[col];
                }
            }
        }
}

// ---------------- aggregate + ReLU: one wave per (row, batch) ----------------
__global__ __launch_bounds__(256) void agg_relu(
    const unsigned short* __restrict__ sup, const float2* __restrict__ epack,
    const int* __restrict__ offsets, const int* __restrict__ counts,
    float* __restrict__ outv)
{
    const int widx = (blockIdx.x * 256 + threadIdx.x) >> 6;
    if (widx >= 2 * NN) return;
    const int lane = threadIdx.x & 63;
    const int b = widx & 1, r = widx >> 1;
    const int d = lane * 4;
    const size_t supb = (size_t)b * NN * DO + d;
    const int start = offsets[r];
    const int deg   = counts[r];

    float a0 = 0.f, a1 = 0.f, a2 = 0.f, a3 = 0.f;
    #pragma unroll 8
    for (int i = 0; i < deg; ++i) {
        const float2 ep = epack[start + i];
        const int col = __float_as_int(ep.x);
        const float v = ep.y;
        const ushort4 s = *(const ushort4*)&sup[supb + (size_t)col * DO];
        a0 += v * bf2f(s.x); a1 += v * bf2f(s.y);
        a2 += v * bf2f(s.z); a3 += v * bf2f(s.w);
    }

    float* o = &outv[((size_t)b * NN + r) * DO + d];
    float4 t4 = *(const float4*)o;
    t4.x = fmaxf(t4.x + a0, 0.f); t4.y = fmaxf(t4.y + a1, 0.f);
    t4.z = fmaxf(t4.z + a2, 0.f); t4.w = fmaxf(t4.w + a3, 0.f);
    *(float4*)o = t4;
}

extern "C" void kernel_launch(void* const* d_in, const int* in_sizes, int n_in,
                              void* d_out, int out_size, void* d_ws, size_t ws_size,
                              hipStream_t stream)
{
    const float* x    = (const float*)d_in[0];
    const float* W    = (const float*)d_in[1];
    const float* LW   = (const float*)d_in[2];
    const float* bias = (const float*)d_in[3];
    const float* ev   = (const float*)d_in[4];
    const int*   rows = (const int*)d_in[5];
    const int*   cols = (const int*)d_in[6];
    float* out = (float*)d_out;

    const int E = in_sizes[4];
    const int EB = (E + 255) / 256;                 // edge blocks
    const int gemmBlocks = ((MT + 63) / 64) * 4;    // 313*4 = 1252

    // workspace layout
    char* wsb = (char*)d_ws;
    unsigned short* Wt    = (unsigned short*)wsb;              // 131,072 B
    unsigned short* LWt   = (unsigned short*)(wsb + 131072);   // 131,072 B
    unsigned short* supb  = (unsigned short*)(wsb + 262144);   // 10,240,000 B
    int* counts  = (int*)(wsb + 10502144);                     // 40,000 B
    int* offsets = (int*)(wsb + 10542144);                     // 40,000 B
    int* cursor  = (int*)(wsb + 10582144);                     // 40,000 B
    float2* epack = (float2*)(wsb + 10622144);                 // 8*E B

    hipMemsetAsync(counts, 0, NN * sizeof(int), stream);

    prep_kernel<<<32 + EB, 256, 0, stream>>>(W, LW, Wt, LWt, rows, counts, E);
    scan_rows<<<1, SCAN_T, 0, stream>>>(counts, offsets, cursor);
    main_kernel<<<gemmBlocks + EB, 256, 0, stream>>>(
        x, Wt, LWt, bias, supb, out, rows, cols, ev, cursor, epack, E, gemmBlocks);

    const int aggBlocks = (2 * NN * 64 + 255) / 256;
    agg_relu<<<aggBlocks, 256, 0, stream>>>(supb, epack, offsets, counts, out);
}